// Round 6
// baseline (1217.170 us; speedup 1.0000x reference)
//
#include <hip/hip_runtime.h>
#include <hip/hip_bf16.h>

#define N_NODES 25000
#define N_EDGES 400000
#define MAXS 475008              // max padded slots (400000 + 25000*3, rounded to 16)
#define NB_EDGE 3711             // edge-kernel blocks (grid-stride, ~2 tiles/wave)

typedef __attribute__((ext_vector_type(8))) short short8;
typedef __attribute__((ext_vector_type(4))) float f32x4;

__device__ __forceinline__ float silu_f(float x) { return x / (1.0f + __expf(-x)); }

__device__ __forceinline__ short f2bf_s(float x) {
  __hip_bfloat16 h = __float2bfloat16(x);
  return *reinterpret_cast<short*>(&h);
}
__device__ __forceinline__ float bf_s2f(short s) {
  __hip_bfloat16 h = *reinterpret_cast<__hip_bfloat16*>(&s);
  return __bfloat162float(h);
}

// ---------------------------------------------------------------------------
// CSR build with per-row padding to multiple of 4 slots.
// ---------------------------------------------------------------------------
__global__ __launch_bounds__(256) void k_hist(const int* __restrict__ rows, int* __restrict__ deg) {
  int e = blockIdx.x * 256 + threadIdx.x;
  if (e < N_EDGES) atomicAdd(&deg[rows[e]], 1);
}

__global__ __launch_bounds__(1024) void k_scan(const int* __restrict__ deg,
                                               int* __restrict__ slotStart,
                                               int* __restrict__ cur) {
  __shared__ int sums[1024];
  const int t = threadIdx.x;
  const int CH = 25;                 // 1024*25 = 25600 >= 25000
  int base = t * CH;
  int local[CH];
  int s = 0;
#pragma unroll
  for (int i = 0; i < CH; ++i) {
    int idx = base + i;
    int d = (idx < N_NODES) ? ((deg[idx] + 3) & ~3) : 0;   // padded degree
    local[i] = s;
    s += d;
  }
  sums[t] = s;
  __syncthreads();
  for (int off = 1; off < 1024; off <<= 1) {
    int v = (t >= off) ? sums[t - off] : 0;
    __syncthreads();
    sums[t] += v;
    __syncthreads();
  }
  int pre = (t == 0) ? 0 : sums[t - 1];
#pragma unroll
  for (int i = 0; i < CH; ++i) {
    int idx = base + i;
    if (idx < N_NODES) {
      int v = pre + local[i];
      slotStart[idx] = v;
      cur[idx] = v;
    }
  }
  if (t == 1023) slotStart[N_NODES] = sums[1023];
}

__global__ __launch_bounds__(256) void k_scatter(
    const int* __restrict__ rows, const int* __restrict__ cols, const float* __restrict__ eatt,
    int* __restrict__ cur, int* __restrict__ prow, int* __restrict__ pcol, float* __restrict__ pea) {
  int e = blockIdx.x * 256 + threadIdx.x;
  if (e < N_EDGES) {
    int r = rows[e];
    int pos = atomicAdd(&cur[r], 1);
    prow[pos] = r;
    pcol[pos] = cols[e];
    pea[pos] = eatt[e];
  }
}

// fill dummy slots (pcol sign bit = dummy marker)
__global__ __launch_bounds__(256) void k_pad(
    const int* __restrict__ deg, const int* __restrict__ slotStart,
    int* __restrict__ prow, int* __restrict__ pcol, float* __restrict__ pea) {
  int n = blockIdx.x * 256 + threadIdx.x;
  if (n < N_NODES) {
    int s0 = slotStart[n] + deg[n];
    int s1 = slotStart[n + 1];
    for (int s = s0; s < s1; ++s) {
      prow[s] = n;
      pcol[s] = (int)0x80000000;   // dummy: col 0, masked out in epilogue
      pea[s] = 0.f;
    }
  }
}

// ---------------------------------------------------------------------------
// Embedding: h = silu([h_g0|h_g1] @ Wg1 + bg1) @ Wg2 + bg2
// ---------------------------------------------------------------------------
__global__ __launch_bounds__(256) void k_embed(
    const float* __restrict__ nodes, const float* __restrict__ W_emb, const float* __restrict__ b_emb,
    const float* __restrict__ Wg1, const float* __restrict__ bg1,
    const float* __restrict__ Wg2, const float* __restrict__ bg2,
    float* __restrict__ h)
{
  __shared__ float We[5 * 64];
  __shared__ float W1[128 * 64];
  __shared__ float W2[64 * 64];
  __shared__ float be[64], b1s[64], b2s[64];
  __shared__ __align__(16) float hbuf[4][128];
  __shared__ __align__(16) float tbuf[4][64];

  for (int t = threadIdx.x; t < 128 * 64; t += 256) W1[t] = Wg1[t];
  for (int t = threadIdx.x; t < 64 * 64; t += 256) W2[t] = Wg2[t];
  for (int t = threadIdx.x; t < 5 * 64; t += 256) We[t] = W_emb[t];
  if (threadIdx.x < 64) {
    be[threadIdx.x]  = b_emb[threadIdx.x];
    b1s[threadIdx.x] = bg1[threadIdx.x];
    b2s[threadIdx.x] = bg2[threadIdx.x];
  }
  __syncthreads();

  const int lane = threadIdx.x & 63;
  const int wv = threadIdx.x >> 6;
  float* hb = hbuf[wv];
  float* tb = tbuf[wv];
  const float4* hb4 = (const float4*)hb;
  const float4* tb4 = (const float4*)tb;

  int n0 = blockIdx.x * 32 + wv * 8;
  int n1 = min(n0 + 8, N_NODES);
  for (int n = n0; n < n1; ++n) {
    float x0 = nodes[n * 5 + 0], x1 = nodes[n * 5 + 1],
          x2 = nodes[n * 5 + 2], x3 = nodes[n * 5 + 3],
          x4 = nodes[n * 5 + 4];
    float w0 = We[0 * 64 + lane], w1 = We[1 * 64 + lane], w2 = We[2 * 64 + lane],
          w3 = We[3 * 64 + lane], w4 = We[4 * 64 + lane];
    float base = be[lane] + x4 * w4;
    float s = x0 * w0 + x1 * w1 + x2 * w2 + x3 * w3;
    hb[lane] = base + s;
    hb[64 + lane] = base - s;
    __builtin_amdgcn_wave_barrier();

    float t = b1s[lane];
#pragma unroll
    for (int k4 = 0; k4 < 32; ++k4) {
      float4 hh = hb4[k4];
      t += hh.x * W1[(4 * k4 + 0) * 64 + lane];
      t += hh.y * W1[(4 * k4 + 1) * 64 + lane];
      t += hh.z * W1[(4 * k4 + 2) * 64 + lane];
      t += hh.w * W1[(4 * k4 + 3) * 64 + lane];
    }
    t = silu_f(t);
    __builtin_amdgcn_wave_barrier();
    tb[lane] = t;
    __builtin_amdgcn_wave_barrier();

    float o = b2s[lane];
#pragma unroll
    for (int k4 = 0; k4 < 16; ++k4) {
      float4 tt = tb4[k4];
      o += tt.x * W2[(4 * k4 + 0) * 64 + lane];
      o += tt.y * W2[(4 * k4 + 1) * 64 + lane];
      o += tt.z * W2[(4 * k4 + 2) * 64 + lane];
      o += tt.w * W2[(4 * k4 + 3) * 64 + lane];
    }
    h[n * 64 + lane] = o;
    __builtin_amdgcn_wave_barrier();
  }
}

// ---------------------------------------------------------------------------
// Node precompute (layer 0 only): u = h @ eW1[0:64], v = h @ eW1[64:128]
// ---------------------------------------------------------------------------
__global__ __launch_bounds__(256) void k_node_pre(
    const float* __restrict__ h, const float* __restrict__ eW1,
    float* __restrict__ u, float* __restrict__ v)
{
  const int lane = threadIdx.x & 63;
  const int wv = threadIdx.x >> 6;
  float ar[64], br[64];
#pragma unroll
  for (int k = 0; k < 64; ++k) {
    ar[k] = eW1[k * 64 + lane];
    br[k] = eW1[(64 + k) * 64 + lane];
  }
  __shared__ __align__(16) float hbuf[4][64];
  float* hb = hbuf[wv];
  const float4* hb4 = (const float4*)hb;

  int nw = gridDim.x * 4;
  int wid = blockIdx.x * 4 + wv;
  int per = (N_NODES + nw - 1) / nw;
  int n0 = wid * per, n1 = min(N_NODES, n0 + per);
  for (int n = n0; n < n1; ++n) {
    hb[lane] = h[n * 64 + lane];
    __builtin_amdgcn_wave_barrier();
    float uu = 0.f, vv = 0.f;
#pragma unroll
    for (int k4 = 0; k4 < 16; ++k4) {
      float4 hh = hb4[k4];
      uu += hh.x * ar[4 * k4 + 0]; vv += hh.x * br[4 * k4 + 0];
      uu += hh.y * ar[4 * k4 + 1]; vv += hh.y * br[4 * k4 + 1];
      uu += hh.z * ar[4 * k4 + 2]; vv += hh.z * br[4 * k4 + 2];
      uu += hh.w * ar[4 * k4 + 3]; vv += hh.w * br[4 * k4 + 3];
    }
    u[n * 64 + lane] = uu;
    v[n * 64 + lane] = vv;
    __builtin_amdgcn_wave_barrier();
  }
}

// ---------------------------------------------------------------------------
// Edge kernel over padded CSR slots, 16-slot tiles. Each 4-slot reg-group
// belongs to ONE node (padding invariant) -> register-reduce 4 silu'd values
// -> one fire-and-forget global_atomic_add per group per 16-feature column.
// ---------------------------------------------------------------------------
__global__ __launch_bounds__(256) void k_edge(
    const float* __restrict__ u, const float* __restrict__ v,
    const int* __restrict__ slotTotalPtr,
    const int* __restrict__ prow, const int* __restrict__ pcol, const float* __restrict__ pea,
    const float* __restrict__ wea, const float* __restrict__ eb1,
    const float* __restrict__ W2, const float* __restrict__ eb2,
    float* __restrict__ agg)
{
  const int lane = threadIdx.x & 63;
  const int wv = threadIdx.x >> 6;
  const int n16 = lane & 15;
  const int quad = lane >> 4;

  // B fragments (W2 columns), split hi/lo, resident in VGPRs.
  short8 Whi[2][4], Wlo[2][4];
#pragma unroll
  for (int s = 0; s < 2; ++s) {
#pragma unroll
    for (int nt = 0; nt < 4; ++nt) {
#pragma unroll
      for (int j = 0; j < 8; ++j) {
        float w2v = W2[(s * 32 + quad * 8 + j) * 64 + nt * 16 + n16];
        short hi = f2bf_s(w2v);
        Whi[s][nt][j] = hi;
        Wlo[s][nt][j] = f2bf_s(w2v - bf_s2f(hi));
      }
    }
  }
  float we = wea[lane];
  float b1v = eb1[lane];
  float b2v[4];
#pragma unroll
  for (int nt = 0; nt < 4; ++nt) b2v[nt] = eb2[nt * 16 + n16];

  __shared__ float Tl[4][64 * 17];   // [feat][slot], pad 17
  float* T = Tl[wv];

  const int slotTotal = *slotTotalPtr;
  const int ntiles = (slotTotal + 15) >> 4;
  const int nwaves = gridDim.x * 4;
  const int wid = blockIdx.x * 4 + wv;

  for (int tile = wid; tile < ntiles; tile += nwaves) {
    int e0 = tile * 16;
    int sl = e0 + n16;
    int msk = (sl < slotTotal) ? 1 : 0;
    if (sl >= slotTotal) sl = slotTotal - 1;
    int r16 = prow[sl];
    int craw = pcol[sl];
    if (craw < 0) msk = 0;
    int c16 = craw & 0x7fffffff;
    float ea16 = pea[sl];

    // phase 1: 16 slots, lane = feature (rows sorted -> u loads ~broadcast)
#pragma unroll 4
    for (int e = 0; e < 16; ++e) {
      int r = __shfl(r16, e);
      int c = __shfl(c16, e);
      float ea = __shfl(ea16, e);
      float t = u[r * 64 + lane] + v[c * 64 + lane] + ea * we + b1v;
      T[lane * 17 + e] = silu_f(t);
    }
    __builtin_amdgcn_wave_barrier();

    f32x4 acc[4] = {};
#pragma unroll
    for (int s = 0; s < 2; ++s) {
      short8 ahi, alo;
#pragma unroll
      for (int j = 0; j < 8; ++j) {
        float tv = T[(s * 32 + quad * 8 + j) * 17 + n16];
        short hi = f2bf_s(tv);
        ahi[j] = hi;
        alo[j] = f2bf_s(tv - bf_s2f(hi));
      }
#pragma unroll
      for (int nt = 0; nt < 4; ++nt) {
        acc[nt] = __builtin_amdgcn_mfma_f32_16x16x32_bf16(ahi, Whi[s][nt], acc[nt], 0, 0, 0);
        acc[nt] = __builtin_amdgcn_mfma_f32_16x16x32_bf16(ahi, Wlo[s][nt], acc[nt], 0, 0, 0);
        acc[nt] = __builtin_amdgcn_mfma_f32_16x16x32_bf16(alo, Whi[s][nt], acc[nt], 0, 0, 0);
      }
    }
    __builtin_amdgcn_wave_barrier();

    // epilogue: this quad's 4-slot group = one node. Register-reduce, 1 atomic/nt.
    int m0 = quad * 4;
    int row_g = __shfl(r16, m0);
    float rm[4];
#pragma unroll
    for (int reg = 0; reg < 4; ++reg) rm[reg] = (float)__shfl(msk, m0 + reg);
#pragma unroll
    for (int nt = 0; nt < 4; ++nt) {
      float s = 0.f;
#pragma unroll
      for (int reg = 0; reg < 4; ++reg)
        s += rm[reg] * silu_f(acc[nt][reg] + b2v[nt]);
      unsafeAtomicAdd(&agg[row_g * 64 + nt * 16 + n16], s);
    }
    __builtin_amdgcn_wave_barrier();
  }
}

// ---------------------------------------------------------------------------
// Fused node MLP + next-layer precompute:
//   phase A: t = silu(h@nW1a + agg@nW1b + nb1)  -> LDS
//   phase B: h_new = t @ nW2 + nb2              -> global h + LDS
//   phase C: u = h_new @ eW1n[0:64], v = h_new @ eW1n[64:128]
// Weight registers reused across phases (wa/wb reassigned).
// ---------------------------------------------------------------------------
__global__ __launch_bounds__(256, 2) void k_node_post(
    float* __restrict__ h, const float* __restrict__ agg,
    const float* __restrict__ nW1, const float* __restrict__ nb1,
    const float* __restrict__ nW2, const float* __restrict__ nb2,
    const float* __restrict__ eW1n,
    float* __restrict__ u, float* __restrict__ v)
{
  const int lane = threadIdx.x & 63;
  const int wv = threadIdx.x >> 6;
  const int wid = blockIdx.x * 4 + wv;
  const int n0 = wid * 8;
  if (n0 >= N_NODES) return;
  const int nn = min(8, N_NODES - n0);

  __shared__ __align__(16) float hbuf[4][64];
  __shared__ __align__(16) float abuf[4][64];
  __shared__ __align__(16) float tst[4][8][68];
  __shared__ __align__(16) float hnw[4][8][68];
  float* hb = hbuf[wv]; float* ab = abuf[wv];
  const float4* hb4 = (const float4*)hb;
  const float4* ab4 = (const float4*)ab;

  float wa[64], wb[64];
#pragma unroll
  for (int k = 0; k < 64; ++k) {
    wa[k] = nW1[k * 64 + lane];
    wb[k] = nW1[(64 + k) * 64 + lane];
  }
  float b1v = nb1[lane], b2v = nb2[lane];

  // phase A
  for (int i = 0; i < nn; ++i) {
    int n = n0 + i;
    hb[lane] = h[n * 64 + lane];
    ab[lane] = agg[n * 64 + lane];
    __builtin_amdgcn_wave_barrier();
    float t = b1v;
#pragma unroll
    for (int k4 = 0; k4 < 16; ++k4) {
      float4 hh = hb4[k4];
      float4 aa = ab4[k4];
      t += hh.x * wa[4 * k4 + 0] + aa.x * wb[4 * k4 + 0];
      t += hh.y * wa[4 * k4 + 1] + aa.y * wb[4 * k4 + 1];
      t += hh.z * wa[4 * k4 + 2] + aa.z * wb[4 * k4 + 2];
      t += hh.w * wa[4 * k4 + 3] + aa.w * wb[4 * k4 + 3];
    }
    tst[wv][i][lane] = silu_f(t);
    __builtin_amdgcn_wave_barrier();
  }

  // phase B: wa <- nW2
#pragma unroll
  for (int k = 0; k < 64; ++k) wa[k] = nW2[k * 64 + lane];
  for (int i = 0; i < nn; ++i) {
    const float4* tt4 = (const float4*)tst[wv][i];
    float o = b2v;
#pragma unroll
    for (int k4 = 0; k4 < 16; ++k4) {
      float4 tt = tt4[k4];
      o += tt.x * wa[4 * k4 + 0];
      o += tt.y * wa[4 * k4 + 1];
      o += tt.z * wa[4 * k4 + 2];
      o += tt.w * wa[4 * k4 + 3];
    }
    h[(n0 + i) * 64 + lane] = o;
    hnw[wv][i][lane] = o;
  }
  __builtin_amdgcn_wave_barrier();

  // phase C: wa/wb <- eW1n
#pragma unroll
  for (int k = 0; k < 64; ++k) {
    wa[k] = eW1n[k * 64 + lane];
    wb[k] = eW1n[(64 + k) * 64 + lane];
  }
  for (int i = 0; i < nn; ++i) {
    const float4* hh4 = (const float4*)hnw[wv][i];
    float uu = 0.f, vv = 0.f;
#pragma unroll
    for (int k4 = 0; k4 < 16; ++k4) {
      float4 hh = hh4[k4];
      uu += hh.x * wa[4 * k4 + 0]; vv += hh.x * wb[4 * k4 + 0];
      uu += hh.y * wa[4 * k4 + 1]; vv += hh.y * wb[4 * k4 + 1];
      uu += hh.z * wa[4 * k4 + 2]; vv += hh.z * wb[4 * k4 + 2];
      uu += hh.w * wa[4 * k4 + 3]; vv += hh.w * wb[4 * k4 + 3];
    }
    u[(n0 + i) * 64 + lane] = uu;
    v[(n0 + i) * 64 + lane] = vv;
  }
}

// ---------------------------------------------------------------------------
// Final node MLP: out = silu(concat(h,agg) @ dnW1 + dnb1) @ dnW2 + dnb2, (N,4)
// ---------------------------------------------------------------------------
__global__ __launch_bounds__(256, 2) void k_node_final(
    const float* __restrict__ h, const float* __restrict__ agg,
    const float* __restrict__ dnW1, const float* __restrict__ dnb1,
    const float* __restrict__ dnW2, const float* __restrict__ dnb2,
    float* __restrict__ out)
{
  const int lane = threadIdx.x & 63;
  const int wv = threadIdx.x >> 6;
  const int wid = blockIdx.x * 4 + wv;
  const int n0 = wid * 8;
  if (n0 >= N_NODES) return;
  const int nn = min(8, N_NODES - n0);

  float ar[64], br[64], wr[64];
#pragma unroll
  for (int k = 0; k < 64; ++k) {
    ar[k] = dnW1[k * 64 + lane];
    br[k] = dnW1[(64 + k) * 64 + lane];
    wr[k] = dnW2[k * 4 + (lane & 3)];
  }
  float b1v = dnb1[lane];
  float b2v = dnb2[lane & 3];
  __shared__ __align__(16) float hbuf[4][64];
  __shared__ __align__(16) float abuf[4][64];
  __shared__ __align__(16) float tbuf[4][64];
  float* hb = hbuf[wv]; float* ab = abuf[wv]; float* tb = tbuf[wv];
  const float4* hb4 = (const float4*)hb;
  const float4* ab4 = (const float4*)ab;
  const float4* tb4 = (const float4*)tb;

  for (int i = 0; i < nn; ++i) {
    int n = n0 + i;
    hb[lane] = h[n * 64 + lane];
    ab[lane] = agg[n * 64 + lane];
    __builtin_amdgcn_wave_barrier();
    float t = b1v;
#pragma unroll
    for (int k4 = 0; k4 < 16; ++k4) {
      float4 hh = hb4[k4];
      float4 aa = ab4[k4];
      t += hh.x * ar[4 * k4 + 0] + aa.x * br[4 * k4 + 0];
      t += hh.y * ar[4 * k4 + 1] + aa.y * br[4 * k4 + 1];
      t += hh.z * ar[4 * k4 + 2] + aa.z * br[4 * k4 + 2];
      t += hh.w * ar[4 * k4 + 3] + aa.w * br[4 * k4 + 3];
    }
    t = silu_f(t);
    __builtin_amdgcn_wave_barrier();
    tb[lane] = t;
    __builtin_amdgcn_wave_barrier();
    float o = b2v;
#pragma unroll
    for (int k4 = 0; k4 < 16; ++k4) {
      float4 tt = tb4[k4];
      o += tt.x * wr[4 * k4 + 0];
      o += tt.y * wr[4 * k4 + 1];
      o += tt.z * wr[4 * k4 + 2];
      o += tt.w * wr[4 * k4 + 3];
    }
    if (lane < 4) out[n * 4 + lane] = o;
    __builtin_amdgcn_wave_barrier();
  }
}

extern "C" void kernel_launch(void* const* d_in, const int* in_sizes, int n_in,
                              void* d_out, int out_size, void* d_ws, size_t ws_size,
                              hipStream_t stream)
{
  const float* nodes = (const float*)d_in[0];
  const int*   edges = (const int*)d_in[1];
  const float* eatt  = (const float*)d_in[2];
  const float* W_emb = (const float*)d_in[3];
  const float* b_emb = (const float*)d_in[4];
  const float* Wg1   = (const float*)d_in[5];
  const float* bg1   = (const float*)d_in[6];
  const float* Wg2   = (const float*)d_in[7];
  const float* bg2   = (const float*)d_in[8];
  const float* eW1   = (const float*)d_in[9];
  const float* eb1   = (const float*)d_in[10];
  const float* eW2   = (const float*)d_in[11];
  const float* eb2   = (const float*)d_in[12];
  const float* nW1   = (const float*)d_in[13];
  const float* nb1   = (const float*)d_in[14];
  const float* nW2   = (const float*)d_in[15];
  const float* nb2   = (const float*)d_in[16];
  const float* deW1  = (const float*)d_in[17];
  const float* deb1  = (const float*)d_in[18];
  const float* deW2  = (const float*)d_in[19];
  const float* deb2  = (const float*)d_in[20];
  const float* dnW1  = (const float*)d_in[21];
  const float* dnb1  = (const float*)d_in[22];
  const float* dnW2  = (const float*)d_in[23];
  const float* dnb2  = (const float*)d_in[24];
  float* out = (float*)d_out;

  float* h    = (float*)d_ws;                 // N*64
  float* u    = h + N_NODES * 64;
  float* v    = u + N_NODES * 64;
  float* agg  = v + N_NODES * 64;
  float* pea  = agg + N_NODES * 64;           // MAXS
  int* deg       = (int*)(pea + MAXS);
  int* cur       = deg + N_NODES;
  int* slotStart = cur + N_NODES;             // N+1
  int* prow      = slotStart + N_NODES + 1;   // MAXS
  int* pcol      = prow + MAXS;               // MAXS

  const int* rows = edges;
  const int* cols = edges + N_EDGES;

  // ---- padded CSR build (once; shared by all 6 GCLs) ----
  hipMemsetAsync(deg, 0, N_NODES * sizeof(int), stream);
  k_hist<<<(N_EDGES + 255) / 256, 256, 0, stream>>>(rows, deg);
  k_scan<<<1, 1024, 0, stream>>>(deg, slotStart, cur);
  k_scatter<<<(N_EDGES + 255) / 256, 256, 0, stream>>>(rows, cols, eatt, cur, prow, pcol, pea);
  k_pad<<<(N_NODES + 255) / 256, 256, 0, stream>>>(deg, slotStart, prow, pcol, pea);

  k_embed<<<(N_NODES + 31) / 32, 256, 0, stream>>>(nodes, W_emb, b_emb, Wg1, bg1, Wg2, bg2, h);
  k_node_pre<<<1024, 256, 0, stream>>>(h, eW1, u, v);   // layer-0 u,v

  const int node_blocks = (N_NODES + 31) / 32;          // 8 nodes/wave, 4 waves/block
  for (int i = 0; i < 5; ++i) {
    const float* W1i = eW1 + i * 129 * 64;
    const float* W1n = (i < 4) ? (eW1 + (i + 1) * 129 * 64) : deW1;
    hipMemsetAsync(agg, 0, N_NODES * 64 * sizeof(float), stream);
    k_edge<<<NB_EDGE, 256, 0, stream>>>(u, v, slotStart + N_NODES, prow, pcol, pea,
                                        W1i + 128 * 64, eb1 + i * 64,
                                        eW2 + i * 64 * 64, eb2 + i * 64, agg);
    k_node_post<<<node_blocks, 256, 0, stream>>>(h, agg, nW1 + i * 128 * 64, nb1 + i * 64,
                                                 nW2 + i * 64 * 64, nb2 + i * 64,
                                                 W1n, u, v);
  }
  // decoder GCL
  hipMemsetAsync(agg, 0, N_NODES * 64 * sizeof(float), stream);
  k_edge<<<NB_EDGE, 256, 0, stream>>>(u, v, slotStart + N_NODES, prow, pcol, pea,
                                      deW1 + 128 * 64, deb1, deW2, deb2, agg);
  k_node_final<<<node_blocks, 256, 0, stream>>>(h, agg, dnW1, dnb1, dnW2, dnb2, out);
}

// Round 7
// 1205.857 us; speedup vs baseline: 1.0094x; 1.0094x over previous
//
#include <hip/hip_runtime.h>
#include <hip/hip_bf16.h>

#define N_NODES 25000
#define N_EDGES 400000
#define MAXS 475008              // max padded slots (400000 + 25000*3, rounded to 16)
#define NB_EDGE 3711             // edge-kernel blocks (grid-stride)

typedef __attribute__((ext_vector_type(8))) short short8;
typedef __attribute__((ext_vector_type(4))) float f32x4;

__device__ __forceinline__ float silu_f(float x) { return x / (1.0f + __expf(-x)); }

__device__ __forceinline__ short f2bf_s(float x) {
  __hip_bfloat16 h = __float2bfloat16(x);
  return *reinterpret_cast<short*>(&h);
}
__device__ __forceinline__ float bf_s2f(short s) {
  __hip_bfloat16 h = *reinterpret_cast<__hip_bfloat16*>(&s);
  return __bfloat162float(h);
}

// ---------------------------------------------------------------------------
// CSR build with per-row padding to multiple of 4 slots.
// ---------------------------------------------------------------------------
__global__ __launch_bounds__(256) void k_hist(const int* __restrict__ rows, int* __restrict__ deg) {
  int e = blockIdx.x * 256 + threadIdx.x;
  if (e < N_EDGES) atomicAdd(&deg[rows[e]], 1);
}

__global__ __launch_bounds__(1024) void k_scan(const int* __restrict__ deg,
                                               int* __restrict__ slotStart,
                                               int* __restrict__ cur) {
  __shared__ int sums[1024];
  const int t = threadIdx.x;
  const int CH = 25;                 // 1024*25 = 25600 >= 25000
  int base = t * CH;
  int local[CH];
  int s = 0;
#pragma unroll
  for (int i = 0; i < CH; ++i) {
    int idx = base + i;
    int d = (idx < N_NODES) ? ((deg[idx] + 3) & ~3) : 0;   // padded degree
    local[i] = s;
    s += d;
  }
  sums[t] = s;
  __syncthreads();
  for (int off = 1; off < 1024; off <<= 1) {
    int v = (t >= off) ? sums[t - off] : 0;
    __syncthreads();
    sums[t] += v;
    __syncthreads();
  }
  int pre = (t == 0) ? 0 : sums[t - 1];
#pragma unroll
  for (int i = 0; i < CH; ++i) {
    int idx = base + i;
    if (idx < N_NODES) {
      int v = pre + local[i];
      slotStart[idx] = v;
      cur[idx] = v;
    }
  }
  if (t == 1023) slotStart[N_NODES] = sums[1023];
}

__global__ __launch_bounds__(256) void k_scatter(
    const int* __restrict__ rows, const int* __restrict__ cols, const float* __restrict__ eatt,
    int* __restrict__ cur, int* __restrict__ prow, int* __restrict__ pcol, float* __restrict__ pea) {
  int e = blockIdx.x * 256 + threadIdx.x;
  if (e < N_EDGES) {
    int r = rows[e];
    int pos = atomicAdd(&cur[r], 1);
    prow[pos] = r;
    pcol[pos] = cols[e];
    pea[pos] = eatt[e];
  }
}

// fill dummy slots (pcol sign bit = dummy marker)
__global__ __launch_bounds__(256) void k_pad(
    const int* __restrict__ deg, const int* __restrict__ slotStart,
    int* __restrict__ prow, int* __restrict__ pcol, float* __restrict__ pea) {
  int n = blockIdx.x * 256 + threadIdx.x;
  if (n < N_NODES) {
    int s0 = slotStart[n] + deg[n];
    int s1 = slotStart[n + 1];
    for (int s = s0; s < s1; ++s) {
      prow[s] = n;
      pcol[s] = (int)0x80000000;   // dummy: col 0, masked out in epilogue
      pea[s] = 0.f;
    }
  }
}

// ---------------------------------------------------------------------------
// Embedding: h = silu([h_g0|h_g1] @ Wg1 + bg1) @ Wg2 + bg2
// ---------------------------------------------------------------------------
__global__ __launch_bounds__(256) void k_embed(
    const float* __restrict__ nodes, const float* __restrict__ W_emb, const float* __restrict__ b_emb,
    const float* __restrict__ Wg1, const float* __restrict__ bg1,
    const float* __restrict__ Wg2, const float* __restrict__ bg2,
    float* __restrict__ h)
{
  __shared__ float We[5 * 64];
  __shared__ float W1[128 * 64];
  __shared__ float W2[64 * 64];
  __shared__ float be[64], b1s[64], b2s[64];
  __shared__ __align__(16) float hbuf[4][128];
  __shared__ __align__(16) float tbuf[4][64];

  for (int t = threadIdx.x; t < 128 * 64; t += 256) W1[t] = Wg1[t];
  for (int t = threadIdx.x; t < 64 * 64; t += 256) W2[t] = Wg2[t];
  for (int t = threadIdx.x; t < 5 * 64; t += 256) We[t] = W_emb[t];
  if (threadIdx.x < 64) {
    be[threadIdx.x]  = b_emb[threadIdx.x];
    b1s[threadIdx.x] = bg1[threadIdx.x];
    b2s[threadIdx.x] = bg2[threadIdx.x];
  }
  __syncthreads();

  const int lane = threadIdx.x & 63;
  const int wv = threadIdx.x >> 6;
  float* hb = hbuf[wv];
  float* tb = tbuf[wv];
  const float4* hb4 = (const float4*)hb;
  const float4* tb4 = (const float4*)tb;

  int n0 = blockIdx.x * 32 + wv * 8;
  int n1 = min(n0 + 8, N_NODES);
  for (int n = n0; n < n1; ++n) {
    float x0 = nodes[n * 5 + 0], x1 = nodes[n * 5 + 1],
          x2 = nodes[n * 5 + 2], x3 = nodes[n * 5 + 3],
          x4 = nodes[n * 5 + 4];
    float w0 = We[0 * 64 + lane], w1 = We[1 * 64 + lane], w2 = We[2 * 64 + lane],
          w3 = We[3 * 64 + lane], w4 = We[4 * 64 + lane];
    float base = be[lane] + x4 * w4;
    float s = x0 * w0 + x1 * w1 + x2 * w2 + x3 * w3;
    hb[lane] = base + s;
    hb[64 + lane] = base - s;
    __builtin_amdgcn_wave_barrier();

    float t = b1s[lane];
#pragma unroll
    for (int k4 = 0; k4 < 32; ++k4) {
      float4 hh = hb4[k4];
      t += hh.x * W1[(4 * k4 + 0) * 64 + lane];
      t += hh.y * W1[(4 * k4 + 1) * 64 + lane];
      t += hh.z * W1[(4 * k4 + 2) * 64 + lane];
      t += hh.w * W1[(4 * k4 + 3) * 64 + lane];
    }
    t = silu_f(t);
    __builtin_amdgcn_wave_barrier();
    tb[lane] = t;
    __builtin_amdgcn_wave_barrier();

    float o = b2s[lane];
#pragma unroll
    for (int k4 = 0; k4 < 16; ++k4) {
      float4 tt = tb4[k4];
      o += tt.x * W2[(4 * k4 + 0) * 64 + lane];
      o += tt.y * W2[(4 * k4 + 1) * 64 + lane];
      o += tt.z * W2[(4 * k4 + 2) * 64 + lane];
      o += tt.w * W2[(4 * k4 + 3) * 64 + lane];
    }
    h[n * 64 + lane] = o;
    __builtin_amdgcn_wave_barrier();
  }
}

// ---------------------------------------------------------------------------
// Node precompute (layer 0 only): u = h @ eW1[0:64], v = h @ eW1[64:128]
// ---------------------------------------------------------------------------
__global__ __launch_bounds__(256)
__attribute__((amdgpu_waves_per_eu(1, 2)))
void k_node_pre(
    const float* __restrict__ h, const float* __restrict__ eW1,
    float* __restrict__ u, float* __restrict__ v)
{
  const int lane = threadIdx.x & 63;
  const int wv = threadIdx.x >> 6;
  float ar[64], br[64];
#pragma unroll
  for (int k = 0; k < 64; ++k) {
    ar[k] = eW1[k * 64 + lane];
    br[k] = eW1[(64 + k) * 64 + lane];
  }
  __shared__ __align__(16) float hbuf[4][64];
  float* hb = hbuf[wv];
  const float4* hb4 = (const float4*)hb;

  int nw = gridDim.x * 4;
  int wid = blockIdx.x * 4 + wv;
  int per = (N_NODES + nw - 1) / nw;
  int n0 = wid * per, n1 = min(N_NODES, n0 + per);
  for (int n = n0; n < n1; ++n) {
    hb[lane] = h[n * 64 + lane];
    __builtin_amdgcn_wave_barrier();
    float u0 = 0.f, u1 = 0.f, v0 = 0.f, v1 = 0.f;
#pragma unroll
    for (int k4 = 0; k4 < 16; ++k4) {
      float4 hh = hb4[k4];
      u0 += hh.x * ar[4 * k4 + 0]; v0 += hh.x * br[4 * k4 + 0];
      u1 += hh.y * ar[4 * k4 + 1]; v1 += hh.y * br[4 * k4 + 1];
      u0 += hh.z * ar[4 * k4 + 2]; v0 += hh.z * br[4 * k4 + 2];
      u1 += hh.w * ar[4 * k4 + 3]; v1 += hh.w * br[4 * k4 + 3];
    }
    u[n * 64 + lane] = u0 + u1;
    v[n * 64 + lane] = v0 + v1;
    __builtin_amdgcn_wave_barrier();
  }
}

// ---------------------------------------------------------------------------
// Edge kernel over padded CSR slots, 16-slot tiles. Each 4-slot reg-group
// belongs to ONE node -> register-reduce 4 silu'd values -> one atomic.
// ---------------------------------------------------------------------------
__global__ __launch_bounds__(256) void k_edge(
    const float* __restrict__ u, const float* __restrict__ v,
    const int* __restrict__ slotTotalPtr,
    const int* __restrict__ prow, const int* __restrict__ pcol, const float* __restrict__ pea,
    const float* __restrict__ wea, const float* __restrict__ eb1,
    const float* __restrict__ W2, const float* __restrict__ eb2,
    float* __restrict__ agg)
{
  const int lane = threadIdx.x & 63;
  const int wv = threadIdx.x >> 6;
  const int n16 = lane & 15;
  const int quad = lane >> 4;

  // B fragments (W2 columns), split hi/lo, resident in VGPRs.
  short8 Whi[2][4], Wlo[2][4];
#pragma unroll
  for (int s = 0; s < 2; ++s) {
#pragma unroll
    for (int nt = 0; nt < 4; ++nt) {
#pragma unroll
      for (int j = 0; j < 8; ++j) {
        float w2v = W2[(s * 32 + quad * 8 + j) * 64 + nt * 16 + n16];
        short hi = f2bf_s(w2v);
        Whi[s][nt][j] = hi;
        Wlo[s][nt][j] = f2bf_s(w2v - bf_s2f(hi));
      }
    }
  }
  float we = wea[lane];
  float b1v = eb1[lane];
  float b2v[4];
#pragma unroll
  for (int nt = 0; nt < 4; ++nt) b2v[nt] = eb2[nt * 16 + n16];

  __shared__ float Tl[4][64 * 17];   // [feat][slot], pad 17
  float* T = Tl[wv];

  const int slotTotal = *slotTotalPtr;
  const int ntiles = (slotTotal + 15) >> 4;
  const int nwaves = gridDim.x * 4;
  const int wid = blockIdx.x * 4 + wv;

  for (int tile = wid; tile < ntiles; tile += nwaves) {
    int e0 = tile * 16;
    int sl = e0 + n16;
    int msk = (sl < slotTotal) ? 1 : 0;
    if (sl >= slotTotal) sl = slotTotal - 1;
    int r16 = prow[sl];
    int craw = pcol[sl];
    if (craw < 0) msk = 0;
    int c16 = craw & 0x7fffffff;
    float ea16 = pea[sl];

    // phase 1: 16 slots, lane = feature (rows sorted -> u loads ~broadcast)
#pragma unroll 4
    for (int e = 0; e < 16; ++e) {
      int r = __shfl(r16, e);
      int c = __shfl(c16, e);
      float ea = __shfl(ea16, e);
      float t = u[r * 64 + lane] + v[c * 64 + lane] + ea * we + b1v;
      T[lane * 17 + e] = silu_f(t);
    }
    __builtin_amdgcn_wave_barrier();

    f32x4 acc[4] = {};
#pragma unroll
    for (int s = 0; s < 2; ++s) {
      short8 ahi, alo;
#pragma unroll
      for (int j = 0; j < 8; ++j) {
        float tv = T[(s * 32 + quad * 8 + j) * 17 + n16];
        short hi = f2bf_s(tv);
        ahi[j] = hi;
        alo[j] = f2bf_s(tv - bf_s2f(hi));
      }
#pragma unroll
      for (int nt = 0; nt < 4; ++nt) {
        acc[nt] = __builtin_amdgcn_mfma_f32_16x16x32_bf16(ahi, Whi[s][nt], acc[nt], 0, 0, 0);
        acc[nt] = __builtin_amdgcn_mfma_f32_16x16x32_bf16(ahi, Wlo[s][nt], acc[nt], 0, 0, 0);
        acc[nt] = __builtin_amdgcn_mfma_f32_16x16x32_bf16(alo, Whi[s][nt], acc[nt], 0, 0, 0);
      }
    }
    __builtin_amdgcn_wave_barrier();

    // epilogue: this quad's 4-slot group = one node. Register-reduce, 1 atomic/nt.
    int m0 = quad * 4;
    int row_g = __shfl(r16, m0);
    float rm[4];
#pragma unroll
    for (int reg = 0; reg < 4; ++reg) rm[reg] = (float)__shfl(msk, m0 + reg);
#pragma unroll
    for (int nt = 0; nt < 4; ++nt) {
      float s = 0.f;
#pragma unroll
      for (int reg = 0; reg < 4; ++reg)
        s += rm[reg] * silu_f(acc[nt][reg] + b2v[nt]);
      unsafeAtomicAdd(&agg[row_g * 64 + nt * 16 + n16], s);
    }
    __builtin_amdgcn_wave_barrier();
  }
}

// ---------------------------------------------------------------------------
// Fused node MLP + next-layer precompute (phased weights, <=128 floats live):
//   phase A: t = silu(h@nW1a + agg@nW1b + nb1) -> LDS; agg[n] <- 0 for next layer
//   phase B: h_new = t @ nW2 + nb2             -> global h + LDS
//   phase C: u = h_new @ eW1n[0:64], v = h_new @ eW1n[64:128]
// ---------------------------------------------------------------------------
__global__ __launch_bounds__(256)
__attribute__((amdgpu_waves_per_eu(1, 2)))
void k_node_post(
    float* __restrict__ h, float* __restrict__ agg,
    const float* __restrict__ nW1, const float* __restrict__ nb1,
    const float* __restrict__ nW2, const float* __restrict__ nb2,
    const float* __restrict__ eW1n,
    float* __restrict__ u, float* __restrict__ v)
{
  const int lane = threadIdx.x & 63;
  const int wv = threadIdx.x >> 6;
  const int wid = blockIdx.x * 4 + wv;
  const int n0 = wid * 8;
  if (n0 >= N_NODES) return;
  const int nn = min(8, N_NODES - n0);

  __shared__ __align__(16) float hbuf[4][64];
  __shared__ __align__(16) float abuf[4][64];
  __shared__ __align__(16) float tst[4][8][68];
  __shared__ __align__(16) float hnw[4][8][68];
  float* hb = hbuf[wv]; float* ab = abuf[wv];
  const float4* hb4 = (const float4*)hb;
  const float4* ab4 = (const float4*)ab;

  float wa[64], wb[64];
#pragma unroll
  for (int k = 0; k < 64; ++k) {
    wa[k] = nW1[k * 64 + lane];
    wb[k] = nW1[(64 + k) * 64 + lane];
  }
  float b1v = nb1[lane], b2v = nb2[lane];

  // phase A
  for (int i = 0; i < nn; ++i) {
    int n = n0 + i;
    hb[lane] = h[n * 64 + lane];
    ab[lane] = agg[n * 64 + lane];
    agg[n * 64 + lane] = 0.f;     // re-zero for next layer's k_edge
    __builtin_amdgcn_wave_barrier();
    float t0 = b1v, t1 = 0.f, t2 = 0.f, t3 = 0.f;
#pragma unroll
    for (int k4 = 0; k4 < 16; ++k4) {
      float4 hh = hb4[k4];
      float4 aa = ab4[k4];
      t0 += hh.x * wa[4 * k4 + 0] + aa.x * wb[4 * k4 + 0];
      t1 += hh.y * wa[4 * k4 + 1] + aa.y * wb[4 * k4 + 1];
      t2 += hh.z * wa[4 * k4 + 2] + aa.z * wb[4 * k4 + 2];
      t3 += hh.w * wa[4 * k4 + 3] + aa.w * wb[4 * k4 + 3];
    }
    tst[wv][i][lane] = silu_f((t0 + t1) + (t2 + t3));
    __builtin_amdgcn_wave_barrier();
  }

  // phase B: wa <- nW2
#pragma unroll
  for (int k = 0; k < 64; ++k) wa[k] = nW2[k * 64 + lane];
  for (int i = 0; i < nn; ++i) {
    const float4* tt4 = (const float4*)tst[wv][i];
    float o0 = b2v, o1 = 0.f, o2 = 0.f, o3 = 0.f;
#pragma unroll
    for (int k4 = 0; k4 < 16; ++k4) {
      float4 tt = tt4[k4];
      o0 += tt.x * wa[4 * k4 + 0];
      o1 += tt.y * wa[4 * k4 + 1];
      o2 += tt.z * wa[4 * k4 + 2];
      o3 += tt.w * wa[4 * k4 + 3];
    }
    float o = (o0 + o1) + (o2 + o3);
    h[(n0 + i) * 64 + lane] = o;
    hnw[wv][i][lane] = o;
  }
  __builtin_amdgcn_wave_barrier();

  // phase C: wa/wb <- eW1n
#pragma unroll
  for (int k = 0; k < 64; ++k) {
    wa[k] = eW1n[k * 64 + lane];
    wb[k] = eW1n[(64 + k) * 64 + lane];
  }
  for (int i = 0; i < nn; ++i) {
    const float4* hh4 = (const float4*)hnw[wv][i];
    float u0 = 0.f, u1 = 0.f, v0 = 0.f, v1 = 0.f;
#pragma unroll
    for (int k4 = 0; k4 < 16; ++k4) {
      float4 hh = hh4[k4];
      u0 += hh.x * wa[4 * k4 + 0]; v0 += hh.x * wb[4 * k4 + 0];
      u1 += hh.y * wa[4 * k4 + 1]; v1 += hh.y * wb[4 * k4 + 1];
      u0 += hh.z * wa[4 * k4 + 2]; v0 += hh.z * wb[4 * k4 + 2];
      u1 += hh.w * wa[4 * k4 + 3]; v1 += hh.w * wb[4 * k4 + 3];
    }
    u[(n0 + i) * 64 + lane] = u0 + u1;
    v[(n0 + i) * 64 + lane] = v0 + v1;
  }
}

// ---------------------------------------------------------------------------
// Final node MLP (phased, <=128 weight floats live):
//   phase A: t = silu(concat(h,agg)@dnW1 + dnb1) -> LDS
//   phase B: out = t @ dnW2 + dnb2, (N,4)
// ---------------------------------------------------------------------------
__global__ __launch_bounds__(256)
__attribute__((amdgpu_waves_per_eu(1, 2)))
void k_node_final(
    const float* __restrict__ h, const float* __restrict__ agg,
    const float* __restrict__ dnW1, const float* __restrict__ dnb1,
    const float* __restrict__ dnW2, const float* __restrict__ dnb2,
    float* __restrict__ out)
{
  const int lane = threadIdx.x & 63;
  const int wv = threadIdx.x >> 6;
  const int wid = blockIdx.x * 4 + wv;
  const int n0 = wid * 8;
  if (n0 >= N_NODES) return;
  const int nn = min(8, N_NODES - n0);

  __shared__ __align__(16) float hbuf[4][64];
  __shared__ __align__(16) float abuf[4][64];
  __shared__ __align__(16) float tst[4][8][68];
  float* hb = hbuf[wv]; float* ab = abuf[wv];
  const float4* hb4 = (const float4*)hb;
  const float4* ab4 = (const float4*)ab;

  float wa[64], wb[64];
#pragma unroll
  for (int k = 0; k < 64; ++k) {
    wa[k] = dnW1[k * 64 + lane];
    wb[k] = dnW1[(64 + k) * 64 + lane];
  }
  float b1v = dnb1[lane];

  // phase A
  for (int i = 0; i < nn; ++i) {
    int n = n0 + i;
    hb[lane] = h[n * 64 + lane];
    ab[lane] = agg[n * 64 + lane];
    __builtin_amdgcn_wave_barrier();
    float t0 = b1v, t1 = 0.f, t2 = 0.f, t3 = 0.f;
#pragma unroll
    for (int k4 = 0; k4 < 16; ++k4) {
      float4 hh = hb4[k4];
      float4 aa = ab4[k4];
      t0 += hh.x * wa[4 * k4 + 0] + aa.x * wb[4 * k4 + 0];
      t1 += hh.y * wa[4 * k4 + 1] + aa.y * wb[4 * k4 + 1];
      t2 += hh.z * wa[4 * k4 + 2] + aa.z * wb[4 * k4 + 2];
      t3 += hh.w * wa[4 * k4 + 3] + aa.w * wb[4 * k4 + 3];
    }
    tst[wv][i][lane] = silu_f((t0 + t1) + (t2 + t3));
    __builtin_amdgcn_wave_barrier();
  }

  // phase B: wa <- dnW2 column for this lane's output m = lane&3
#pragma unroll
  for (int k = 0; k < 64; ++k) wa[k] = dnW2[k * 4 + (lane & 3)];
  float b2v = dnb2[lane & 3];
  for (int i = 0; i < nn; ++i) {
    const float4* tt4 = (const float4*)tst[wv][i];
    float o0 = b2v, o1 = 0.f, o2 = 0.f, o3 = 0.f;
#pragma unroll
    for (int k4 = 0; k4 < 16; ++k4) {
      float4 tt = tt4[k4];
      o0 += tt.x * wa[4 * k4 + 0];
      o1 += tt.y * wa[4 * k4 + 1];
      o2 += tt.z * wa[4 * k4 + 2];
      o3 += tt.w * wa[4 * k4 + 3];
    }
    if (lane < 4) out[(n0 + i) * 4 + lane] = (o0 + o1) + (o2 + o3);
    __builtin_amdgcn_wave_barrier();
  }
}

extern "C" void kernel_launch(void* const* d_in, const int* in_sizes, int n_in,
                              void* d_out, int out_size, void* d_ws, size_t ws_size,
                              hipStream_t stream)
{
  const float* nodes = (const float*)d_in[0];
  const int*   edges = (const int*)d_in[1];
  const float* eatt  = (const float*)d_in[2];
  const float* W_emb = (const float*)d_in[3];
  const float* b_emb = (const float*)d_in[4];
  const float* Wg1   = (const float*)d_in[5];
  const float* bg1   = (const float*)d_in[6];
  const float* Wg2   = (const float*)d_in[7];
  const float* bg2   = (const float*)d_in[8];
  const float* eW1   = (const float*)d_in[9];
  const float* eb1   = (const float*)d_in[10];
  const float* eW2   = (const float*)d_in[11];
  const float* eb2   = (const float*)d_in[12];
  const float* nW1   = (const float*)d_in[13];
  const float* nb1   = (const float*)d_in[14];
  const float* nW2   = (const float*)d_in[15];
  const float* nb2   = (const float*)d_in[16];
  const float* deW1  = (const float*)d_in[17];
  const float* deb1  = (const float*)d_in[18];
  const float* deW2  = (const float*)d_in[19];
  const float* deb2  = (const float*)d_in[20];
  const float* dnW1  = (const float*)d_in[21];
  const float* dnb1  = (const float*)d_in[22];
  const float* dnW2  = (const float*)d_in[23];
  const float* dnb2  = (const float*)d_in[24];
  float* out = (float*)d_out;

  float* h    = (float*)d_ws;                 // N*64
  float* u    = h + N_NODES * 64;
  float* v    = u + N_NODES * 64;
  float* agg  = v + N_NODES * 64;
  float* pea  = agg + N_NODES * 64;           // MAXS
  int* deg       = (int*)(pea + MAXS);
  int* cur       = deg + N_NODES;
  int* slotStart = cur + N_NODES;             // N+1
  int* prow      = slotStart + N_NODES + 1;   // MAXS
  int* pcol      = prow + MAXS;               // MAXS

  const int* rows = edges;
  const int* cols = edges + N_EDGES;

  // ---- padded CSR build (once; shared by all 6 GCLs) ----
  hipMemsetAsync(deg, 0, N_NODES * sizeof(int), stream);
  k_hist<<<(N_EDGES + 255) / 256, 256, 0, stream>>>(rows, deg);
  k_scan<<<1, 1024, 0, stream>>>(deg, slotStart, cur);
  k_scatter<<<(N_EDGES + 255) / 256, 256, 0, stream>>>(rows, cols, eatt, cur, prow, pcol, pea);
  k_pad<<<(N_NODES + 255) / 256, 256, 0, stream>>>(deg, slotStart, prow, pcol, pea);

  k_embed<<<(N_NODES + 31) / 32, 256, 0, stream>>>(nodes, W_emb, b_emb, Wg1, bg1, Wg2, bg2, h);
  k_node_pre<<<1024, 256, 0, stream>>>(h, eW1, u, v);   // layer-0 u,v
  hipMemsetAsync(agg, 0, N_NODES * 64 * sizeof(float), stream);  // only zeroing; node_post re-zeroes

  const int node_blocks = (N_NODES + 31) / 32;          // 8 nodes/wave, 4 waves/block
  for (int i = 0; i < 5; ++i) {
    const float* W1i = eW1 + i * 129 * 64;
    const float* W1n = (i < 4) ? (eW1 + (i + 1) * 129 * 64) : deW1;
    k_edge<<<NB_EDGE, 256, 0, stream>>>(u, v, slotStart + N_NODES, prow, pcol, pea,
                                        W1i + 128 * 64, eb1 + i * 64,
                                        eW2 + i * 64 * 64, eb2 + i * 64, agg);
    k_node_post<<<node_blocks, 256, 0, stream>>>(h, agg, nW1 + i * 128 * 64, nb1 + i * 64,
                                                 nW2 + i * 64 * 64, nb2 + i * 64,
                                                 W1n, u, v);
  }
  // decoder GCL
  k_edge<<<NB_EDGE, 256, 0, stream>>>(u, v, slotStart + N_NODES, prow, pcol, pea,
                                      deW1 + 128 * 64, deb1, deW2, deb2, agg);
  k_node_final<<<node_blocks, 256, 0, stream>>>(h, agg, dnW1, dnb1, dnW2, dnb2, out);
}

// Round 8
// 1165.879 us; speedup vs baseline: 1.0440x; 1.0343x over previous
//
#include <hip/hip_runtime.h>
#include <hip/hip_bf16.h>

#define N_NODES 25000
#define N_EDGES 400000
#define MAXS 475008              // max padded slots (400000 + 25000*3, rounded to 16)
#define NB_EDGE 3711             // edge-kernel blocks (grid-stride)

typedef __attribute__((ext_vector_type(8))) short short8;
typedef __attribute__((ext_vector_type(4))) float f32x4;

__device__ __forceinline__ float silu_f(float x) { return x / (1.0f + __expf(-x)); }

__device__ __forceinline__ short f2bf_s(float x) {
  __hip_bfloat16 h = __float2bfloat16(x);
  return *reinterpret_cast<short*>(&h);
}
__device__ __forceinline__ float bf_s2f(short s) {
  __hip_bfloat16 h = *reinterpret_cast<__hip_bfloat16*>(&s);
  return __bfloat162float(h);
}

// ---------------------------------------------------------------------------
// CSR build with per-row padding to multiple of 4 slots.
// ---------------------------------------------------------------------------
__global__ __launch_bounds__(256) void k_hist(const int* __restrict__ rows, int* __restrict__ deg) {
  int e = blockIdx.x * 256 + threadIdx.x;
  if (e < N_EDGES) atomicAdd(&deg[rows[e]], 1);
}

__global__ __launch_bounds__(1024) void k_scan(const int* __restrict__ deg,
                                               int* __restrict__ slotStart,
                                               int* __restrict__ cur) {
  __shared__ int sums[1024];
  const int t = threadIdx.x;
  const int CH = 25;                 // 1024*25 = 25600 >= 25000
  int base = t * CH;
  int local[CH];
  int s = 0;
#pragma unroll
  for (int i = 0; i < CH; ++i) {
    int idx = base + i;
    int d = (idx < N_NODES) ? ((deg[idx] + 3) & ~3) : 0;   // padded degree
    local[i] = s;
    s += d;
  }
  sums[t] = s;
  __syncthreads();
  for (int off = 1; off < 1024; off <<= 1) {
    int v = (t >= off) ? sums[t - off] : 0;
    __syncthreads();
    sums[t] += v;
    __syncthreads();
  }
  int pre = (t == 0) ? 0 : sums[t - 1];
#pragma unroll
  for (int i = 0; i < CH; ++i) {
    int idx = base + i;
    if (idx < N_NODES) {
      int v = pre + local[i];
      slotStart[idx] = v;
      cur[idx] = v;
    }
  }
  if (t == 1023) slotStart[N_NODES] = sums[1023];
}

__global__ __launch_bounds__(256) void k_scatter(
    const int* __restrict__ rows, const int* __restrict__ cols, const float* __restrict__ eatt,
    int* __restrict__ cur, int* __restrict__ prow, int* __restrict__ pcol, float* __restrict__ pea) {
  int e = blockIdx.x * 256 + threadIdx.x;
  if (e < N_EDGES) {
    int r = rows[e];
    int pos = atomicAdd(&cur[r], 1);
    prow[pos] = r;
    pcol[pos] = cols[e];
    pea[pos] = eatt[e];
  }
}

// fill dummy slots (pcol sign bit = dummy marker)
__global__ __launch_bounds__(256) void k_pad(
    const int* __restrict__ deg, const int* __restrict__ slotStart,
    int* __restrict__ prow, int* __restrict__ pcol, float* __restrict__ pea) {
  int n = blockIdx.x * 256 + threadIdx.x;
  if (n < N_NODES) {
    int s0 = slotStart[n] + deg[n];
    int s1 = slotStart[n + 1];
    for (int s = s0; s < s1; ++s) {
      prow[s] = n;
      pcol[s] = (int)0x80000000;   // dummy
      pea[s] = 0.f;
    }
  }
}

// ---------------------------------------------------------------------------
// Embedding: h = silu([h_g0|h_g1] @ Wg1 + bg1) @ Wg2 + bg2
// ---------------------------------------------------------------------------
__global__ __launch_bounds__(256) void k_embed(
    const float* __restrict__ nodes, const float* __restrict__ W_emb, const float* __restrict__ b_emb,
    const float* __restrict__ Wg1, const float* __restrict__ bg1,
    const float* __restrict__ Wg2, const float* __restrict__ bg2,
    float* __restrict__ h)
{
  __shared__ float We[5 * 64];
  __shared__ float W1[128 * 64];
  __shared__ float W2[64 * 64];
  __shared__ float be[64], b1s[64], b2s[64];
  __shared__ __align__(16) float hbuf[4][128];
  __shared__ __align__(16) float tbuf[4][64];

  for (int t = threadIdx.x; t < 128 * 64; t += 256) W1[t] = Wg1[t];
  for (int t = threadIdx.x; t < 64 * 64; t += 256) W2[t] = Wg2[t];
  for (int t = threadIdx.x; t < 5 * 64; t += 256) We[t] = W_emb[t];
  if (threadIdx.x < 64) {
    be[threadIdx.x]  = b_emb[threadIdx.x];
    b1s[threadIdx.x] = bg1[threadIdx.x];
    b2s[threadIdx.x] = bg2[threadIdx.x];
  }
  __syncthreads();

  const int lane = threadIdx.x & 63;
  const int wv = threadIdx.x >> 6;
  float* hb = hbuf[wv];
  float* tb = tbuf[wv];
  const float4* hb4 = (const float4*)hb;
  const float4* tb4 = (const float4*)tb;

  int n0 = blockIdx.x * 32 + wv * 8;
  int n1 = min(n0 + 8, N_NODES);
  for (int n = n0; n < n1; ++n) {
    float x0 = nodes[n * 5 + 0], x1 = nodes[n * 5 + 1],
          x2 = nodes[n * 5 + 2], x3 = nodes[n * 5 + 3],
          x4 = nodes[n * 5 + 4];
    float w0 = We[0 * 64 + lane], w1 = We[1 * 64 + lane], w2 = We[2 * 64 + lane],
          w3 = We[3 * 64 + lane], w4 = We[4 * 64 + lane];
    float base = be[lane] + x4 * w4;
    float s = x0 * w0 + x1 * w1 + x2 * w2 + x3 * w3;
    hb[lane] = base + s;
    hb[64 + lane] = base - s;
    __builtin_amdgcn_wave_barrier();

    float t = b1s[lane];
#pragma unroll
    for (int k4 = 0; k4 < 32; ++k4) {
      float4 hh = hb4[k4];
      t += hh.x * W1[(4 * k4 + 0) * 64 + lane];
      t += hh.y * W1[(4 * k4 + 1) * 64 + lane];
      t += hh.z * W1[(4 * k4 + 2) * 64 + lane];
      t += hh.w * W1[(4 * k4 + 3) * 64 + lane];
    }
    t = silu_f(t);
    __builtin_amdgcn_wave_barrier();
    tb[lane] = t;
    __builtin_amdgcn_wave_barrier();

    float o = b2s[lane];
#pragma unroll
    for (int k4 = 0; k4 < 16; ++k4) {
      float4 tt = tb4[k4];
      o += tt.x * W2[(4 * k4 + 0) * 64 + lane];
      o += tt.y * W2[(4 * k4 + 1) * 64 + lane];
      o += tt.z * W2[(4 * k4 + 2) * 64 + lane];
      o += tt.w * W2[(4 * k4 + 3) * 64 + lane];
    }
    h[n * 64 + lane] = o;
    __builtin_amdgcn_wave_barrier();
  }
}

// ---------------------------------------------------------------------------
// u,v precompute (every layer): u = h @ eW1[0:64], v = h @ eW1[64:128]
// Weights staged in LDS per block; 8 nodes/wave with batched prefetch.
// ---------------------------------------------------------------------------
__global__ __launch_bounds__(256) void k_node_uv(
    const float* __restrict__ h, const float* __restrict__ eW1,
    float* __restrict__ u, float* __restrict__ v)
{
  __shared__ float Ws[128 * 64];                      // 32 KB
  __shared__ __align__(16) float hbuf[4][8][64];      // 8 KB

  for (int t = threadIdx.x; t < 128 * 64; t += 256) Ws[t] = eW1[t];
  __syncthreads();

  const int lane = threadIdx.x & 63;
  const int wv = threadIdx.x >> 6;
  const int n0 = (blockIdx.x * 4 + wv) * 8;
  if (n0 >= N_NODES) return;
  const int nn = min(8, N_NODES - n0);

  float h8[8];
#pragma unroll
  for (int i = 0; i < 8; ++i) if (i < nn) h8[i] = h[(n0 + i) * 64 + lane];
#pragma unroll
  for (int i = 0; i < 8; ++i) if (i < nn) hbuf[wv][i][lane] = h8[i];
  __builtin_amdgcn_wave_barrier();

  for (int i = 0; i < nn; ++i) {
    const float4* hh4 = (const float4*)hbuf[wv][i];
    float u0 = 0.f, u1 = 0.f, v0 = 0.f, v1 = 0.f;
#pragma unroll
    for (int k4 = 0; k4 < 16; ++k4) {
      float4 hh = hh4[k4];
      u0 += hh.x * Ws[(4 * k4 + 0) * 64 + lane]; v0 += hh.x * Ws[(64 + 4 * k4 + 0) * 64 + lane];
      u1 += hh.y * Ws[(4 * k4 + 1) * 64 + lane]; v1 += hh.y * Ws[(64 + 4 * k4 + 1) * 64 + lane];
      u0 += hh.z * Ws[(4 * k4 + 2) * 64 + lane]; v0 += hh.z * Ws[(64 + 4 * k4 + 2) * 64 + lane];
      u1 += hh.w * Ws[(4 * k4 + 3) * 64 + lane]; v1 += hh.w * Ws[(64 + 4 * k4 + 3) * 64 + lane];
    }
    u[(n0 + i) * 64 + lane] = u0 + u1;
    v[(n0 + i) * 64 + lane] = v0 + v1;
  }
}

// ---------------------------------------------------------------------------
// Edge kernel over padded CSR slots (unchanged from R7).
// ---------------------------------------------------------------------------
__global__ __launch_bounds__(256) void k_edge(
    const float* __restrict__ u, const float* __restrict__ v,
    const int* __restrict__ slotTotalPtr,
    const int* __restrict__ prow, const int* __restrict__ pcol, const float* __restrict__ pea,
    const float* __restrict__ wea, const float* __restrict__ eb1,
    const float* __restrict__ W2, const float* __restrict__ eb2,
    float* __restrict__ agg)
{
  const int lane = threadIdx.x & 63;
  const int wv = threadIdx.x >> 6;
  const int n16 = lane & 15;
  const int quad = lane >> 4;

  short8 Whi[2][4], Wlo[2][4];
#pragma unroll
  for (int s = 0; s < 2; ++s) {
#pragma unroll
    for (int nt = 0; nt < 4; ++nt) {
#pragma unroll
      for (int j = 0; j < 8; ++j) {
        float w2v = W2[(s * 32 + quad * 8 + j) * 64 + nt * 16 + n16];
        short hi = f2bf_s(w2v);
        Whi[s][nt][j] = hi;
        Wlo[s][nt][j] = f2bf_s(w2v - bf_s2f(hi));
      }
    }
  }
  float we = wea[lane];
  float b1v = eb1[lane];
  float b2v[4];
#pragma unroll
  for (int nt = 0; nt < 4; ++nt) b2v[nt] = eb2[nt * 16 + n16];

  __shared__ float Tl[4][64 * 17];   // [feat][slot], pad 17
  float* T = Tl[wv];

  const int slotTotal = *slotTotalPtr;
  const int ntiles = (slotTotal + 15) >> 4;
  const int nwaves = gridDim.x * 4;
  const int wid = blockIdx.x * 4 + wv;

  for (int tile = wid; tile < ntiles; tile += nwaves) {
    int e0 = tile * 16;
    int sl = e0 + n16;
    int msk = (sl < slotTotal) ? 1 : 0;
    if (sl >= slotTotal) sl = slotTotal - 1;
    int r16 = prow[sl];
    int craw = pcol[sl];
    if (craw < 0) msk = 0;
    int c16 = craw & 0x7fffffff;
    float ea16 = pea[sl];

#pragma unroll 4
    for (int e = 0; e < 16; ++e) {
      int r = __shfl(r16, e);
      int c = __shfl(c16, e);
      float ea = __shfl(ea16, e);
      float t = u[r * 64 + lane] + v[c * 64 + lane] + ea * we + b1v;
      T[lane * 17 + e] = silu_f(t);
    }
    __builtin_amdgcn_wave_barrier();

    f32x4 acc[4] = {};
#pragma unroll
    for (int s = 0; s < 2; ++s) {
      short8 ahi, alo;
#pragma unroll
      for (int j = 0; j < 8; ++j) {
        float tv = T[(s * 32 + quad * 8 + j) * 17 + n16];
        short hi = f2bf_s(tv);
        ahi[j] = hi;
        alo[j] = f2bf_s(tv - bf_s2f(hi));
      }
#pragma unroll
      for (int nt = 0; nt < 4; ++nt) {
        acc[nt] = __builtin_amdgcn_mfma_f32_16x16x32_bf16(ahi, Whi[s][nt], acc[nt], 0, 0, 0);
        acc[nt] = __builtin_amdgcn_mfma_f32_16x16x32_bf16(ahi, Wlo[s][nt], acc[nt], 0, 0, 0);
        acc[nt] = __builtin_amdgcn_mfma_f32_16x16x32_bf16(alo, Whi[s][nt], acc[nt], 0, 0, 0);
      }
    }
    __builtin_amdgcn_wave_barrier();

    int m0 = quad * 4;
    int row_g = __shfl(r16, m0);
    float rm[4];
#pragma unroll
    for (int reg = 0; reg < 4; ++reg) rm[reg] = (float)__shfl(msk, m0 + reg);
#pragma unroll
    for (int nt = 0; nt < 4; ++nt) {
      float s = 0.f;
#pragma unroll
      for (int reg = 0; reg < 4; ++reg)
        s += rm[reg] * silu_f(acc[nt][reg] + b2v[nt]);
      unsafeAtomicAdd(&agg[row_g * 64 + nt * 16 + n16], s);
    }
    __builtin_amdgcn_wave_barrier();
  }
}

// ---------------------------------------------------------------------------
// Node MLP (phases A+B): h = silu(h@nW1a + agg@nW1b + nb1) @ nW2 + nb2
// nW1 in LDS per block; nW2 in VGPRs; 8 nodes/wave with batched prefetch.
// Also re-zeros agg for the next layer's k_edge.
// ---------------------------------------------------------------------------
__global__ __launch_bounds__(256) void k_node_post(
    float* __restrict__ h, float* __restrict__ agg,
    const float* __restrict__ nW1, const float* __restrict__ nb1,
    const float* __restrict__ nW2, const float* __restrict__ nb2)
{
  __shared__ float W1s[128 * 64];                     // 32 KB
  __shared__ float b1s[64], b2s[64];
  __shared__ __align__(16) float hbuf[4][8][64];      // 8 KB (reused for t)
  __shared__ __align__(16) float abuf[4][8][64];      // 8 KB

  for (int t = threadIdx.x; t < 128 * 64; t += 256) W1s[t] = nW1[t];
  if (threadIdx.x < 64) {
    b1s[threadIdx.x] = nb1[threadIdx.x];
    b2s[threadIdx.x] = nb2[threadIdx.x];
  }
  const int lane = threadIdx.x & 63;
  const int wv = threadIdx.x >> 6;
  float w2r[64];
#pragma unroll
  for (int k = 0; k < 64; ++k) w2r[k] = nW2[k * 64 + lane];
  __syncthreads();

  const int n0 = (blockIdx.x * 4 + wv) * 8;
  if (n0 >= N_NODES) return;
  const int nn = min(8, N_NODES - n0);

  // batched prefetch: one latency exposure per wave
  float h8[8], a8[8];
#pragma unroll
  for (int i = 0; i < 8; ++i) if (i < nn) {
    h8[i] = h[(n0 + i) * 64 + lane];
    a8[i] = agg[(n0 + i) * 64 + lane];
  }
#pragma unroll
  for (int i = 0; i < 8; ++i) if (i < nn) {
    hbuf[wv][i][lane] = h8[i];
    abuf[wv][i][lane] = a8[i];
    agg[(n0 + i) * 64 + lane] = 0.f;   // re-zero for next layer
  }
  __builtin_amdgcn_wave_barrier();

  // phase A
  float t8[8];
  for (int i = 0; i < nn; ++i) {
    const float4* hh4 = (const float4*)hbuf[wv][i];
    const float4* aa4 = (const float4*)abuf[wv][i];
    float t0 = b1s[lane], t1 = 0.f, t2 = 0.f, t3 = 0.f;
#pragma unroll
    for (int k4 = 0; k4 < 16; ++k4) {
      float4 hh = hh4[k4];
      float4 aa = aa4[k4];
      t0 += hh.x * W1s[(4 * k4 + 0) * 64 + lane] + aa.x * W1s[(64 + 4 * k4 + 0) * 64 + lane];
      t1 += hh.y * W1s[(4 * k4 + 1) * 64 + lane] + aa.y * W1s[(64 + 4 * k4 + 1) * 64 + lane];
      t2 += hh.z * W1s[(4 * k4 + 2) * 64 + lane] + aa.z * W1s[(64 + 4 * k4 + 2) * 64 + lane];
      t3 += hh.w * W1s[(4 * k4 + 3) * 64 + lane] + aa.w * W1s[(64 + 4 * k4 + 3) * 64 + lane];
    }
    t8[i] = silu_f((t0 + t1) + (t2 + t3));
  }
  __builtin_amdgcn_wave_barrier();
#pragma unroll
  for (int i = 0; i < 8; ++i) if (i < nn) hbuf[wv][i][lane] = t8[i];
  __builtin_amdgcn_wave_barrier();

  // phase B (weights in VGPRs)
  for (int i = 0; i < nn; ++i) {
    const float4* tt4 = (const float4*)hbuf[wv][i];
    float o0 = b2s[lane], o1 = 0.f, o2 = 0.f, o3 = 0.f;
#pragma unroll
    for (int k4 = 0; k4 < 16; ++k4) {
      float4 tt = tt4[k4];
      o0 += tt.x * w2r[4 * k4 + 0];
      o1 += tt.y * w2r[4 * k4 + 1];
      o2 += tt.z * w2r[4 * k4 + 2];
      o3 += tt.w * w2r[4 * k4 + 3];
    }
    h[(n0 + i) * 64 + lane] = (o0 + o1) + (o2 + o3);
  }
}

// ---------------------------------------------------------------------------
// Final node MLP: out = silu(concat(h,agg)@dnW1 + dnb1) @ dnW2 + dnb2, (N,4)
// ---------------------------------------------------------------------------
__global__ __launch_bounds__(256) void k_node_final(
    const float* __restrict__ h, const float* __restrict__ agg,
    const float* __restrict__ dnW1, const float* __restrict__ dnb1,
    const float* __restrict__ dnW2, const float* __restrict__ dnb2,
    float* __restrict__ out)
{
  __shared__ float W1s[128 * 64];                     // 32 KB
  __shared__ float b1s[64];
  __shared__ __align__(16) float hbuf[4][8][64];
  __shared__ __align__(16) float abuf[4][8][64];

  for (int t = threadIdx.x; t < 128 * 64; t += 256) W1s[t] = dnW1[t];
  if (threadIdx.x < 64) b1s[threadIdx.x] = dnb1[threadIdx.x];
  const int lane = threadIdx.x & 63;
  const int wv = threadIdx.x >> 6;
  float wr[64];
#pragma unroll
  for (int k = 0; k < 64; ++k) wr[k] = dnW2[k * 4 + (lane & 3)];
  float b2v = dnb2[lane & 3];
  __syncthreads();

  const int n0 = (blockIdx.x * 4 + wv) * 8;
  if (n0 >= N_NODES) return;
  const int nn = min(8, N_NODES - n0);

  float h8[8], a8[8];
#pragma unroll
  for (int i = 0; i < 8; ++i) if (i < nn) {
    h8[i] = h[(n0 + i) * 64 + lane];
    a8[i] = agg[(n0 + i) * 64 + lane];
  }
#pragma unroll
  for (int i = 0; i < 8; ++i) if (i < nn) {
    hbuf[wv][i][lane] = h8[i];
    abuf[wv][i][lane] = a8[i];
  }
  __builtin_amdgcn_wave_barrier();

  float t8[8];
  for (int i = 0; i < nn; ++i) {
    const float4* hh4 = (const float4*)hbuf[wv][i];
    const float4* aa4 = (const float4*)abuf[wv][i];
    float t0 = b1s[lane], t1 = 0.f, t2 = 0.f, t3 = 0.f;
#pragma unroll
    for (int k4 = 0; k4 < 16; ++k4) {
      float4 hh = hh4[k4];
      float4 aa = aa4[k4];
      t0 += hh.x * W1s[(4 * k4 + 0) * 64 + lane] + aa.x * W1s[(64 + 4 * k4 + 0) * 64 + lane];
      t1 += hh.y * W1s[(4 * k4 + 1) * 64 + lane] + aa.y * W1s[(64 + 4 * k4 + 1) * 64 + lane];
      t2 += hh.z * W1s[(4 * k4 + 2) * 64 + lane] + aa.z * W1s[(64 + 4 * k4 + 2) * 64 + lane];
      t3 += hh.w * W1s[(4 * k4 + 3) * 64 + lane] + aa.w * W1s[(64 + 4 * k4 + 3) * 64 + lane];
    }
    t8[i] = silu_f((t0 + t1) + (t2 + t3));
  }
  __builtin_amdgcn_wave_barrier();
#pragma unroll
  for (int i = 0; i < 8; ++i) if (i < nn) hbuf[wv][i][lane] = t8[i];
  __builtin_amdgcn_wave_barrier();

  for (int i = 0; i < nn; ++i) {
    const float4* tt4 = (const float4*)hbuf[wv][i];
    float o0 = b2v, o1 = 0.f, o2 = 0.f, o3 = 0.f;
#pragma unroll
    for (int k4 = 0; k4 < 16; ++k4) {
      float4 tt = tt4[k4];
      o0 += tt.x * wr[4 * k4 + 0];
      o1 += tt.y * wr[4 * k4 + 1];
      o2 += tt.z * wr[4 * k4 + 2];
      o3 += tt.w * wr[4 * k4 + 3];
    }
    if (lane < 4) out[(n0 + i) * 4 + lane] = (o0 + o1) + (o2 + o3);
    __builtin_amdgcn_wave_barrier();
  }
}

extern "C" void kernel_launch(void* const* d_in, const int* in_sizes, int n_in,
                              void* d_out, int out_size, void* d_ws, size_t ws_size,
                              hipStream_t stream)
{
  const float* nodes = (const float*)d_in[0];
  const int*   edges = (const int*)d_in[1];
  const float* eatt  = (const float*)d_in[2];
  const float* W_emb = (const float*)d_in[3];
  const float* b_emb = (const float*)d_in[4];
  const float* Wg1   = (const float*)d_in[5];
  const float* bg1   = (const float*)d_in[6];
  const float* Wg2   = (const float*)d_in[7];
  const float* bg2   = (const float*)d_in[8];
  const float* eW1   = (const float*)d_in[9];
  const float* eb1   = (const float*)d_in[10];
  const float* eW2   = (const float*)d_in[11];
  const float* eb2   = (const float*)d_in[12];
  const float* nW1   = (const float*)d_in[13];
  const float* nb1   = (const float*)d_in[14];
  const float* nW2   = (const float*)d_in[15];
  const float* nb2   = (const float*)d_in[16];
  const float* deW1  = (const float*)d_in[17];
  const float* deb1  = (const float*)d_in[18];
  const float* deW2  = (const float*)d_in[19];
  const float* deb2  = (const float*)d_in[20];
  const float* dnW1  = (const float*)d_in[21];
  const float* dnb1  = (const float*)d_in[22];
  const float* dnW2  = (const float*)d_in[23];
  const float* dnb2  = (const float*)d_in[24];
  float* out = (float*)d_out;

  float* h    = (float*)d_ws;                 // N*64
  float* u    = h + N_NODES * 64;
  float* v    = u + N_NODES * 64;
  float* agg  = v + N_NODES * 64;
  float* pea  = agg + N_NODES * 64;           // MAXS
  int* deg       = (int*)(pea + MAXS);
  int* cur       = deg + N_NODES;
  int* slotStart = cur + N_NODES;             // N+1
  int* prow      = slotStart + N_NODES + 1;   // MAXS
  int* pcol      = prow + MAXS;               // MAXS

  const int* rows = edges;
  const int* cols = edges + N_EDGES;

  // ---- padded CSR build (once; shared by all 6 GCLs) ----
  hipMemsetAsync(deg, 0, N_NODES * sizeof(int), stream);
  k_hist<<<(N_EDGES + 255) / 256, 256, 0, stream>>>(rows, deg);
  k_scan<<<1, 1024, 0, stream>>>(deg, slotStart, cur);
  k_scatter<<<(N_EDGES + 255) / 256, 256, 0, stream>>>(rows, cols, eatt, cur, prow, pcol, pea);
  k_pad<<<(N_NODES + 255) / 256, 256, 0, stream>>>(deg, slotStart, prow, pcol, pea);

  k_embed<<<(N_NODES + 31) / 32, 256, 0, stream>>>(nodes, W_emb, b_emb, Wg1, bg1, Wg2, bg2, h);

  const int node_blocks = (N_NODES + 31) / 32;          // 8 nodes/wave, 4 waves/block
  k_node_uv<<<node_blocks, 256, 0, stream>>>(h, eW1, u, v);     // layer-0 u,v
  hipMemsetAsync(agg, 0, N_NODES * 64 * sizeof(float), stream); // once; node_post re-zeroes

  for (int i = 0; i < 5; ++i) {
    const float* W1i = eW1 + i * 129 * 64;
    const float* W1n = (i < 4) ? (eW1 + (i + 1) * 129 * 64) : deW1;
    k_edge<<<NB_EDGE, 256, 0, stream>>>(u, v, slotStart + N_NODES, prow, pcol, pea,
                                        W1i + 128 * 64, eb1 + i * 64,
                                        eW2 + i * 64 * 64, eb2 + i * 64, agg);
    k_node_post<<<node_blocks, 256, 0, stream>>>(h, agg, nW1 + i * 128 * 64, nb1 + i * 64,
                                                 nW2 + i * 64 * 64, nb2 + i * 64);
    k_node_uv<<<node_blocks, 256, 0, stream>>>(h, W1n, u, v);
  }
  // decoder GCL
  k_edge<<<NB_EDGE, 256, 0, stream>>>(u, v, slotStart + N_NODES, prow, pcol, pea,
                                      deW1 + 128 * 64, deb1, deW2, deb2, agg);
  k_node_final<<<node_blocks, 256, 0, stream>>>(h, agg, dnW1, dnb1, dnW2, dnb2, out);
}